// Round 1
// baseline (366.123 us; speedup 1.0000x reference)
//
#include <hip/hip_runtime.h>
#include <math.h>

#define PCEN_EPS 1e-6f

constexpr int Bn = 64, Cn = 80, Tn = 8000;
constexpr int ROWS = Bn * Cn;             // 5120
constexpr int WPB  = 4;                    // waves per block
constexpr int CHUNK = 256;                 // 64 lanes * float4
constexpr int NCHUNK = (Tn + CHUNK - 1) / CHUNK;  // 32 (last chunk = 64 elems)

static_assert(ROWS % WPB == 0, "grid sizing");

__global__ __launch_bounds__(WPB * 64, 4)
void pcen_kernel(const float* __restrict__ x,
                 const float* __restrict__ logit_s,
                 const float* __restrict__ alpha,
                 const float* __restrict__ delta,
                 const float* __restrict__ log_r,
                 float* __restrict__ out)
{
    const int lane = threadIdx.x & 63;
    const int wid  = threadIdx.x >> 6;
    const int row  = blockIdx.x * WPB + wid;   // one wave per (b,c) row
    const int c    = row % Cn;

    // per-channel parameters (broadcast loads)
    const float s  = 1.0f / (1.0f + __expf(-logit_s[c]));
    const float w  = 1.0f - s;
    const float a  = fminf(fmaxf(alpha[c], 0.1f), 1.0f);
    const float dd = fmaxf(delta[c], 0.1f);
    const float rr = fminf(fmaxf(__expf(log_r[c]), 0.05f), 1.5f);
    const float d_r = __powf(dd, rr);

    // scan coefficients: w4p[i] = w^(4*2^i), built by repeated squaring (no log of ~0)
    float w4p[6];
    w4p[0] = (w * w) * (w * w);
    #pragma unroll
    for (int i = 1; i < 6; ++i) w4p[i] = w4p[i - 1] * w4p[i - 1];
    // per-lane w^(4*lane) via binary expansion of lane
    float w4L = 1.0f;
    #pragma unroll
    for (int b = 0; b < 6; ++b)
        if (lane & (1 << b)) w4L *= w4p[b];

    const float* __restrict__ xrow = x + (size_t)row * Tn;
    float* __restrict__ orow       = out + (size_t)row * Tn;

    // initial carry: P = relu(x[0]); then m_0 = w*x0 + s*x0 = x0 exactly as required
    float P = fmaxf(xrow[0], 0.0f);

    int base = lane * 4;
    float4 xv = *reinterpret_cast<const float4*>(xrow + base);  // chunk 0, all in-bounds

    for (int ch = 0; ch < NCHUNK; ++ch) {
        // --- prefetch next chunk (zero-fill OOB lanes of the tail) ---
        float4 xn = make_float4(0.f, 0.f, 0.f, 0.f);
        const int nbase = base + CHUNK;
        if (ch + 1 < NCHUNK && nbase < Tn)
            xn = *reinterpret_cast<const float4*>(xrow + nbase);

        // --- relu + scaled inputs ---
        const float x0 = fmaxf(xv.x, 0.f), x1 = fmaxf(xv.y, 0.f);
        const float x2 = fmaxf(xv.z, 0.f), x3 = fmaxf(xv.w, 0.f);
        const float u0 = s * x0, u1 = s * x1, u2 = s * x2, u3 = s * x3;

        // lane-local 4-element recurrence end value (carry-in 0):
        // y = ((u0*w + u1)*w + u2)*w + u3
        float y = fmaf(fmaf(fmaf(u0, w, u1), w, u2), w, u3);

        // inclusive Hillis-Steele scan across 64 lanes, coefficient w^4
        float Y = y;
        #pragma unroll
        for (int st = 0; st < 6; ++st) {
            const float Yup  = __shfl_up(Y, 1 << st, 64);
            const float cand = fmaf(w4p[st], Yup, Y);
            Y = (lane >= (1 << st)) ? cand : Y;
        }

        // incoming m-value just before this lane's 4-segment:
        // F_l = w^(4l) * P + Y_{l-1}
        const float Yprev = __shfl_up(Y, 1, 64);
        const float excl  = (lane == 0) ? 0.0f : Yprev;
        const float F     = fmaf(w4L, P, excl);

        // local recurrence m_t = w*m_{t-1} + u_t
        const float m0 = fmaf(w, F,  u0);
        const float m1 = fmaf(w, m0, u1);
        const float m2 = fmaf(w, m1, u2);
        const float m3 = fmaf(w, m2, u3);

        // carry to next chunk = m at last element (lane 63 holds it; zeros in tail don't matter)
        P = __shfl(m3, 63, 64);

        // --- pcen pointwise: (x*(eps+m)^-a + d)^r - d^r ---
        float4 ov;
        ov.x = __powf(fmaf(x0, __powf(PCEN_EPS + m0, -a), dd), rr) - d_r;
        ov.y = __powf(fmaf(x1, __powf(PCEN_EPS + m1, -a), dd), rr) - d_r;
        ov.z = __powf(fmaf(x2, __powf(PCEN_EPS + m2, -a), dd), rr) - d_r;
        ov.w = __powf(fmaf(x3, __powf(PCEN_EPS + m3, -a), dd), rr) - d_r;

        if (base < Tn)
            *reinterpret_cast<float4*>(orow + base) = ov;

        base += CHUNK;
        xv = xn;
    }
}

extern "C" void kernel_launch(void* const* d_in, const int* in_sizes, int n_in,
                              void* d_out, int out_size, void* d_ws, size_t ws_size,
                              hipStream_t stream) {
    const float* features = (const float*)d_in[0];
    const float* logit_s  = (const float*)d_in[1];
    const float* alpha    = (const float*)d_in[2];
    const float* delta    = (const float*)d_in[3];
    const float* log_r    = (const float*)d_in[4];
    float* out = (float*)d_out;

    const int blocks = ROWS / WPB;  // 1280 blocks x 256 threads = 5120 waves
    pcen_kernel<<<blocks, WPB * 64, 0, stream>>>(features, logit_s, alpha, delta, log_r, out);
}

// Round 2
// 70.574 us; speedup vs baseline: 5.1878x; 5.1878x over previous
//
#include <hip/hip_runtime.h>
#include <math.h>

#define PCEN_EPS 1e-6f

constexpr int Bn = 64, Cn = 80, Tn = 8000;
constexpr int ROWS = Bn * Cn;             // 5120
constexpr int WPB  = 4;                    // waves per block
constexpr int CHUNK = 256;                 // 64 lanes * float4
constexpr int NCHUNK = (Tn + CHUNK - 1) / CHUNK;  // 32 (last chunk = 64 elems)

static_assert(ROWS % WPB == 0, "grid sizing");

// Fast pow for strictly-positive base: exp2(e * log2(b)) on the HW
// transcendental pipe (v_log_f32 / v_exp_f32, ~1 ulp each).
// HIP's __powf lowers to __ocml_pow_f32 (~80-inst library call) — that was
// the R1 bottleneck (VALUBusy 97%).
__device__ __forceinline__ float fast_pow_pos(float b, float e) {
#if __has_builtin(__builtin_amdgcn_logf) && __has_builtin(__builtin_amdgcn_exp2f)
    return __builtin_amdgcn_exp2f(e * __builtin_amdgcn_logf(b));
#else
    return __exp2f(e * __log2f(b));
#endif
}

__global__ __launch_bounds__(WPB * 64, 4)
void pcen_kernel(const float* __restrict__ x,
                 const float* __restrict__ logit_s,
                 const float* __restrict__ alpha,
                 const float* __restrict__ delta,
                 const float* __restrict__ log_r,
                 float* __restrict__ out)
{
    const int lane = threadIdx.x & 63;
    const int wid  = threadIdx.x >> 6;
    const int row  = blockIdx.x * WPB + wid;   // one wave per (b,c) row
    const int c    = row % Cn;

    // per-channel parameters (broadcast loads)
    const float s  = 1.0f / (1.0f + __expf(-logit_s[c]));
    const float w  = 1.0f - s;
    const float a  = fminf(fmaxf(alpha[c], 0.1f), 1.0f);
    const float dd = fmaxf(delta[c], 0.1f);
    const float rr = fminf(fmaxf(__expf(log_r[c]), 0.05f), 1.5f);
    const float d_r = fast_pow_pos(dd, rr);
    const float na = -a;

    // scan coefficients: w4p[i] = w^(4*2^i), built by repeated squaring (no log of ~0)
    float w4p[6];
    w4p[0] = (w * w) * (w * w);
    #pragma unroll
    for (int i = 1; i < 6; ++i) w4p[i] = w4p[i - 1] * w4p[i - 1];
    // per-lane w^(4*lane) via binary expansion of lane
    float w4L = 1.0f;
    #pragma unroll
    for (int b = 0; b < 6; ++b)
        if (lane & (1 << b)) w4L *= w4p[b];

    const float* __restrict__ xrow = x + (size_t)row * Tn;
    float* __restrict__ orow       = out + (size_t)row * Tn;

    // initial carry: P = relu(x[0]); then m_0 = w*x0 + s*x0 = x0 exactly as required
    float P = fmaxf(xrow[0], 0.0f);

    int base = lane * 4;
    float4 xv = *reinterpret_cast<const float4*>(xrow + base);  // chunk 0, all in-bounds

    for (int ch = 0; ch < NCHUNK; ++ch) {
        // --- prefetch next chunk (zero-fill OOB lanes of the tail) ---
        float4 xn = make_float4(0.f, 0.f, 0.f, 0.f);
        const int nbase = base + CHUNK;
        if (ch + 1 < NCHUNK && nbase < Tn)
            xn = *reinterpret_cast<const float4*>(xrow + nbase);

        // --- relu + scaled inputs ---
        const float x0 = fmaxf(xv.x, 0.f), x1 = fmaxf(xv.y, 0.f);
        const float x2 = fmaxf(xv.z, 0.f), x3 = fmaxf(xv.w, 0.f);
        const float u0 = s * x0, u1 = s * x1, u2 = s * x2, u3 = s * x3;

        // lane-local 4-element recurrence end value (carry-in 0):
        // y = ((u0*w + u1)*w + u2)*w + u3
        float y = fmaf(fmaf(fmaf(u0, w, u1), w, u2), w, u3);

        // inclusive Hillis-Steele scan across 64 lanes, coefficient w^4
        float Y = y;
        #pragma unroll
        for (int st = 0; st < 6; ++st) {
            const float Yup  = __shfl_up(Y, 1 << st, 64);
            const float cand = fmaf(w4p[st], Yup, Y);
            Y = (lane >= (1 << st)) ? cand : Y;
        }

        // incoming m-value just before this lane's 4-segment:
        // F_l = w^(4l) * P + Y_{l-1}
        const float Yprev = __shfl_up(Y, 1, 64);
        const float excl  = (lane == 0) ? 0.0f : Yprev;
        const float F     = fmaf(w4L, P, excl);

        // local recurrence m_t = w*m_{t-1} + u_t
        const float m0 = fmaf(w, F,  u0);
        const float m1 = fmaf(w, m0, u1);
        const float m2 = fmaf(w, m1, u2);
        const float m3 = fmaf(w, m2, u3);

        // carry to next chunk = m at last element (lane 63 holds it; zeros in tail don't matter)
        P = __shfl(m3, 63, 64);

        // --- pcen pointwise: (x*(eps+m)^-a + d)^r - d^r ---
        // (eps+m)^-a and (...)^r via native exp2/log2; both bases > 0 always.
        const float t0 = fast_pow_pos(PCEN_EPS + m0, na);
        const float t1 = fast_pow_pos(PCEN_EPS + m1, na);
        const float t2 = fast_pow_pos(PCEN_EPS + m2, na);
        const float t3 = fast_pow_pos(PCEN_EPS + m3, na);

        float4 ov;
        ov.x = fast_pow_pos(fmaf(x0, t0, dd), rr) - d_r;
        ov.y = fast_pow_pos(fmaf(x1, t1, dd), rr) - d_r;
        ov.z = fast_pow_pos(fmaf(x2, t2, dd), rr) - d_r;
        ov.w = fast_pow_pos(fmaf(x3, t3, dd), rr) - d_r;

        if (base < Tn)
            *reinterpret_cast<float4*>(orow + base) = ov;

        base += CHUNK;
        xv = xn;
    }
}

extern "C" void kernel_launch(void* const* d_in, const int* in_sizes, int n_in,
                              void* d_out, int out_size, void* d_ws, size_t ws_size,
                              hipStream_t stream) {
    const float* features = (const float*)d_in[0];
    const float* logit_s  = (const float*)d_in[1];
    const float* alpha    = (const float*)d_in[2];
    const float* delta    = (const float*)d_in[3];
    const float* log_r    = (const float*)d_in[4];
    float* out = (float*)d_out;

    const int blocks = ROWS / WPB;  // 1280 blocks x 256 threads = 5120 waves
    pcen_kernel<<<blocks, WPB * 64, 0, stream>>>(features, logit_s, alpha, delta, log_r, out);
}

// Round 3
// 63.878 us; speedup vs baseline: 5.7316x; 1.1048x over previous
//
#include <hip/hip_runtime.h>
#include <math.h>

#define PCEN_EPS 1e-6f

constexpr int Bn = 64, Cn = 80, Tn = 8000;
constexpr int ROWS = Bn * Cn;          // 5120 rows; one block per row
constexpr int WPR  = 4;                // waves per row
constexpr int SEG  = Tn / WPR;         // 2000 elements per wave
constexpr int EPL  = 8;                // elements per lane
constexpr int LCH  = 64 * EPL;         // 512-element chunk
constexpr int NCH  = (SEG + LCH - 1) / LCH;  // 4 chunks (last = 464 elems = 58 lanes)

// pow for strictly-positive base on the HW transcendental pipe
// (v_log_f32 is log2; verified by R2 passing with absmax 0.0156)
__device__ __forceinline__ float fast_pow_pos(float b, float e) {
#if __has_builtin(__builtin_amdgcn_logf) && __has_builtin(__builtin_amdgcn_exp2f)
    return __builtin_amdgcn_exp2f(e * __builtin_amdgcn_logf(b));
#else
    return __exp2f(e * __log2f(b));
#endif
}

__global__ __launch_bounds__(256, 4)
void pcen_kernel(const float* __restrict__ x,
                 const float* __restrict__ logit_s,
                 const float* __restrict__ alpha,
                 const float* __restrict__ delta,
                 const float* __restrict__ log_r,
                 float* __restrict__ out)
{
    __shared__ float sm[WPR];
    const int lane = threadIdx.x & 63;
    const int wid  = threadIdx.x >> 6;
    const int row  = blockIdx.x;           // one block per (b,c) row
    const int c    = row % Cn;

    // per-channel parameters (broadcast loads)
    const float s  = 1.0f / (1.0f + __expf(-logit_s[c]));
    const float w  = 1.0f - s;
    const float a  = fminf(fmaxf(alpha[c], 0.1f), 1.0f);
    const float dd = fmaxf(delta[c], 0.1f);
    const float rr = fminf(fmaxf(__expf(log_r[c]), 0.05f), 1.5f);
    const float d_r = fast_pow_pos(dd, rr);
    const float na  = -a;

    // w8p[i] = w^(8*2^i), i=0..7 (repeated squaring; no log of ~0)
    float w8p[8];
    {
        const float w2 = w * w, w4 = w2 * w2;
        w8p[0] = w4 * w4;
        #pragma unroll
        for (int i = 1; i < 8; ++i) w8p[i] = w8p[i - 1] * w8p[i - 1];
    }
    // per-lane w^(8*lane)
    float w8L = 1.0f;
    #pragma unroll
    for (int b = 0; b < 6; ++b)
        if (lane & (1 << b)) w8L *= w8p[b];
    const float w512 = w8p[6];
    // w^2000 = w^(8*250), 250 = 128+64+32+16+8+2 (may underflow to 0 -> still exact enough)
    const float w2000 = w8p[7] * w8p[6] * w8p[5] * w8p[4] * w8p[3] * w8p[1];

    const float* __restrict__ xs = x   + (size_t)row * Tn + wid * SEG;
    float* __restrict__ os       = out + (size_t)row * Tn + wid * SEG;

    // ---- issue ALL segment loads up-front (8 x float4 per lane in flight) ----
    float xv[NCH][EPL];
    #pragma unroll
    for (int ch = 0; ch < NCH; ++ch) {
        const int base = ch * LCH + lane * EPL;
        if (base + EPL <= SEG) {
            const float4 p0 = *reinterpret_cast<const float4*>(xs + base);
            const float4 p1 = *reinterpret_cast<const float4*>(xs + base + 4);
            xv[ch][0] = p0.x; xv[ch][1] = p0.y; xv[ch][2] = p0.z; xv[ch][3] = p0.w;
            xv[ch][4] = p1.x; xv[ch][5] = p1.y; xv[ch][6] = p1.z; xv[ch][7] = p1.w;
        } else {
            #pragma unroll
            for (int j = 0; j < EPL; ++j) xv[ch][j] = 0.0f;
        }
    }
    // relu in place
    #pragma unroll
    for (int ch = 0; ch < NCH; ++ch)
        #pragma unroll
        for (int j = 0; j < EPL; ++j) xv[ch][j] = fmaxf(xv[ch][j], 0.0f);

    // wave 0 starts with carry P = relu(x[0]) so m_0 = w*x0 + s*x0 = x0 exactly
    float P = __shfl(xv[0][0], 0, 64);
    if (wid != 0) P = 0.0f;

    // ---- phase A: per-wave scan over 4 chunks (carry-in 0 for waves 1..3) ----
    float mv[NCH][EPL];
    #pragma unroll
    for (int ch = 0; ch < NCH; ++ch) {
        // lane-local 8-elem Horner, carry 0: y = sum_j w^(7-j) * s*x_j
        float y = s * xv[ch][0];
        #pragma unroll
        for (int j = 1; j < EPL; ++j) y = fmaf(y, w, s * xv[ch][j]);
        // Hillis-Steele inclusive scan across 64 lanes, coefficient w^8
        float Y = y;
        #pragma unroll
        for (int st = 0; st < 6; ++st) {
            const float Yup  = __shfl_up(Y, 1 << st, 64);
            const float cand = fmaf(w8p[st], Yup, Y);
            Y = (lane >= (1 << st)) ? cand : Y;
        }
        const float Yprev = __shfl_up(Y, 1, 64);
        const float excl  = (lane == 0) ? 0.0f : Yprev;
        const float F     = fmaf(w8L, P, excl);   // m just before this lane's span
        float mm = F;
        #pragma unroll
        for (int j = 0; j < EPL; ++j) { mm = fmaf(w, mm, s * xv[ch][j]); mv[ch][j] = mm; }
        // carry out of chunk: last REAL element (tail chunk ends at lane 57 elem 7)
        P = __shfl(mv[ch][EPL - 1], (ch == NCH - 1) ? 57 : 63, 64);
    }

    // ---- cross-wave carry combine (exact) ----
    if (lane == 0) sm[wid] = P;   // wave0's value already includes the x0 carry
    __syncthreads();
    const float A0 = sm[0];
    const float A1 = fmaf(w2000, A0, sm[1]);
    const float A2 = fmaf(w2000, A1, sm[2]);
    const float Pin = (wid == 1) ? A0 : (wid == 2) ? A1 : (wid == 3) ? A2 : 0.0f;

    // ---- phase B: carry correction m += w^(t+1)*Pin, pointwise pcen, store ----
    float wc = 1.0f;  // w^(ch*512)
    #pragma unroll
    for (int ch = 0; ch < NCH; ++ch) {
        float f = wc * w8L * w;   // w^(ch*512 + lane*8 + 1)
        float ov[EPL];
        #pragma unroll
        for (int j = 0; j < EPL; ++j) {
            const float m = fmaf(f, Pin, mv[ch][j]);
            f *= w;
            const float t = fast_pow_pos(PCEN_EPS + m, na);
            ov[j] = fast_pow_pos(fmaf(xv[ch][j], t, dd), rr) - d_r;
        }
        const int base = ch * LCH + lane * EPL;
        if (base + EPL <= SEG) {
            *reinterpret_cast<float4*>(os + base)     = make_float4(ov[0], ov[1], ov[2], ov[3]);
            *reinterpret_cast<float4*>(os + base + 4) = make_float4(ov[4], ov[5], ov[6], ov[7]);
        }
        wc *= w512;
    }
}

extern "C" void kernel_launch(void* const* d_in, const int* in_sizes, int n_in,
                              void* d_out, int out_size, void* d_ws, size_t ws_size,
                              hipStream_t stream) {
    const float* features = (const float*)d_in[0];
    const float* logit_s  = (const float*)d_in[1];
    const float* alpha    = (const float*)d_in[2];
    const float* delta    = (const float*)d_in[3];
    const float* log_r    = (const float*)d_in[4];
    float* out = (float*)d_out;

    // one block per row: 5120 blocks x 256 threads = 20480 waves
    pcen_kernel<<<ROWS, WPR * 64, 0, stream>>>(features, logit_s, alpha, delta, log_r, out);
}